// Round 3
// baseline (270.438 us; speedup 1.0000x reference)
//
#include <hip/hip_runtime.h>

// N=4096, A=512, C=100 (derived at launch).
// Outputs flat: [loss(1), new_cov(C*A*A), new_ave(C*A), new_amount(C)]

#define TM 128          // cov block tile (TM x TM)
#define KC 32           // members per k-chunk
#define KCP 40          // padded member stride (elems); 40*2B=80B = 5*16B -> b128-aligned rows

typedef __attribute__((ext_vector_type(8))) short bf16x8;   // 8 bf16 = 4 VGPRs (MFMA A/B frag)
typedef __attribute__((ext_vector_type(4))) float f32x4;    // MFMA C/D frag

__device__ __forceinline__ unsigned short f2bf(float f) {   // RNE f32->bf16 bits
    unsigned u = __float_as_uint(f);
    u += 0x7fffu + ((u >> 16) & 1u);
    return (unsigned short)(u >> 16);
}

// ---------------- prep: histogram + scan + per-class scalars + counting-sort scatter ----------------
__global__ __launch_bounds__(1024) void prep_kernel(
    const int* __restrict__ labels, const float* __restrict__ Amount,
    int* __restrict__ offsets, int* __restrict__ idx_sorted,
    float* __restrict__ w_arr, float* __restrict__ inv_cs,
    float* __restrict__ amount_out, float* __restrict__ out_loss0, int N, int C) {
    __shared__ int hist[1024];
    __shared__ int offs[1025];
    __shared__ int cur[1024];
    const int tid = threadIdx.x;
    for (int c = tid; c < C; c += 1024) { hist[c] = 0; cur[c] = 0; }
    __syncthreads();
    for (int i = tid; i < N; i += 1024) atomicAdd(&hist[labels[i]], 1);
    __syncthreads();
    if (tid == 0) {
        int o = 0;
        for (int c = 0; c < C; ++c) { offs[c] = o; o += hist[c]; }
        offs[C] = o;
    }
    __syncthreads();
    for (int c = tid; c < C; c += 1024) {
        float cf = (float)hist[c];
        float cs = cf > 0.f ? cf : 1.f;
        inv_cs[c] = 1.f / cs;
        float am = Amount[c];
        float dn = cf + am;
        w_arr[c] = dn > 0.f ? cf / dn : 0.f;
        amount_out[c] = am + cf;
        offsets[c] = offs[c];
    }
    if (tid == 0) { offsets[C] = offs[C]; out_loss0[0] = 0.f; }
    for (int i = tid; i < N; i += 1024) {
        int c = labels[i];
        int p = atomicAdd(&cur[c], 1);
        idx_sorted[offs[c] + p] = i;
    }
}

// ---------------- per-class mean + fused new_ave; grid (A/128, C), 128 threads ----------------
__global__ __launch_bounds__(128) void ave_kernel(
    const float* __restrict__ feats, const float* __restrict__ Ave_in,
    const int* __restrict__ idx_sorted, const int* __restrict__ offsets,
    const float* __restrict__ w_arr, const float* __restrict__ inv_cs,
    float* __restrict__ ave_new, float* __restrict__ ave_out, int A) {
    __shared__ int idxs[512];
    const int c = blockIdx.y;
    const int col = blockIdx.x * 128 + threadIdx.x;
    const int base = offsets[c];
    const int nc = offsets[c + 1] - base;
    float sum = 0.f;
    for (int i0 = 0; i0 < nc; i0 += 512) {
        int chunk = min(512, nc - i0);
        __syncthreads();
        for (int j = threadIdx.x; j < chunk; j += 128) idxs[j] = idx_sorted[base + i0 + j];
        __syncthreads();
        int j = 0;
        for (; j + 3 < chunk; j += 4) {
            float f0 = feats[(size_t)idxs[j] * A + col];
            float f1 = feats[(size_t)idxs[j + 1] * A + col];
            float f2 = feats[(size_t)idxs[j + 2] * A + col];
            float f3 = feats[(size_t)idxs[j + 3] * A + col];
            sum += f0 + f1 + f2 + f3;
        }
        for (; j < chunk; ++j) sum += feats[(size_t)idxs[j] * A + col];
    }
    float av = sum * inv_cs[c];
    ave_new[(size_t)c * A + col] = av;
    float w = w_arr[c];
    ave_out[(size_t)c * A + col] = Ave_in[(size_t)c * A + col] * (1.f - w) + av * w;
}

// ---------------- cov: block = (class, 128x128 tile), 256 thr = 4 waves, bf16 MFMA ----------------
// wave w owns the 64x64 quadrant (qm=w>>1, qn=w&1) as 4x4 tiles of 16x16.
__global__ __launch_bounds__(256) void cov_kernel(
    const float* __restrict__ feats, const float* __restrict__ cov_in,
    const float* __restrict__ ave_new, const float* __restrict__ Ave_in,
    const int* __restrict__ idx_sorted, const int* __restrict__ offsets,
    const float* __restrict__ w_arr, const float* __restrict__ inv_cs,
    float* __restrict__ cov_out, int A) {
    const int c  = blockIdx.z;
    const int a0 = blockIdx.y * TM;
    const int b0 = blockIdx.x * TM;
    const int tid = threadIdx.x;

    __shared__ __align__(16) unsigned short XT[2][TM][KCP];  // [side][col][member] bf16 bits
    __shared__ float dA[TM], dB[TM];
    __shared__ int idx_lds[KC];

    const float w   = w_arr[c];
    const float omw = 1.f - w;
    const float s   = inv_cs[c] * w;
    const float aw  = w * omw;
    const size_t cbase = (size_t)c * A * A;

    if (s > 0.f) {
        // staging role: each thread owns one column (a-side or b-side)
        const int side = tid >> 7;
        const int col  = tid & 127;
        const int gcol = (side ? b0 : a0) + col;
        const float mean = ave_new[(size_t)c * A + gcol];
        if (side == 0) dA[col] = Ave_in[(size_t)c * A + gcol] - mean;
        else           dB[col] = Ave_in[(size_t)c * A + gcol] - mean;

        // compute role
        const int wave = tid >> 6;
        const int qm = wave >> 1, qn = wave & 1;
        const int lane = tid & 63;
        const int lq = lane >> 4, lr = lane & 15;

        f32x4 acc[4][4];
        if (omw != 0.f) {
            // fold cov_in*(1-w) into accumulator init (C-layout: row=lq*4+reg, col=lr)
            const float sc = omw / s;
            #pragma unroll
            for (int i = 0; i < 4; ++i)
                #pragma unroll
                for (int j = 0; j < 4; ++j) {
                    const int n = qn * 64 + j * 16 + lr;
                    #pragma unroll
                    for (int reg = 0; reg < 4; ++reg) {
                        const int m = qm * 64 + i * 16 + lq * 4 + reg;
                        acc[i][j][reg] = cov_in[cbase + (size_t)(a0 + m) * A + b0 + n] * sc;
                    }
                }
        } else {
            #pragma unroll
            for (int i = 0; i < 4; ++i)
                #pragma unroll
                for (int j = 0; j < 4; ++j)
                    acc[i][j] = (f32x4){0.f, 0.f, 0.f, 0.f};
        }

        const int base = offsets[c];
        const int nc = offsets[c + 1] - base;

        for (int kk = 0; kk < nc; kk += KC) {
            __syncthreads();   // protect prev chunk's XT/idx reads; also makes dA/dB visible
            if (tid < KC) idx_lds[tid] = (kk + tid < nc) ? idx_sorted[base + kk + tid] : 0;
            __syncthreads();
            // stage KC members of this thread's column, bf16, transposed [col][member]
            #pragma unroll
            for (int mg = 0; mg < KC / 4; ++mg) {
                unsigned short q0, q1, q2, q3;
                {
                    int m = mg * 4;
                    float v0 = (kk + m + 0 < nc) ? feats[(size_t)idx_lds[m + 0] * A + gcol] - mean : 0.f;
                    float v1 = (kk + m + 1 < nc) ? feats[(size_t)idx_lds[m + 1] * A + gcol] - mean : 0.f;
                    float v2 = (kk + m + 2 < nc) ? feats[(size_t)idx_lds[m + 2] * A + gcol] - mean : 0.f;
                    float v3 = (kk + m + 3 < nc) ? feats[(size_t)idx_lds[m + 3] * A + gcol] - mean : 0.f;
                    q0 = f2bf(v0); q1 = f2bf(v1); q2 = f2bf(v2); q3 = f2bf(v3);
                }
                uint2 pk;
                pk.x = (unsigned)q0 | ((unsigned)q1 << 16);
                pk.y = (unsigned)q2 | ((unsigned)q3 << 16);
                *reinterpret_cast<uint2*>(&XT[side][col][mg * 4]) = pk;
            }
            __syncthreads();
            // fragments: members contiguous -> one ds_read_b128 per frag
            bf16x8 af[4], bfr[4];
            #pragma unroll
            for (int i = 0; i < 4; ++i)
                af[i] = *reinterpret_cast<const bf16x8*>(&XT[0][qm * 64 + i * 16 + lr][lq * 8]);
            #pragma unroll
            for (int j = 0; j < 4; ++j)
                bfr[j] = *reinterpret_cast<const bf16x8*>(&XT[1][qn * 64 + j * 16 + lr][lq * 8]);
            #pragma unroll
            for (int i = 0; i < 4; ++i)
                #pragma unroll
                for (int j = 0; j < 4; ++j)
                    acc[i][j] = __builtin_amdgcn_mfma_f32_16x16x32_bf16(af[i], bfr[j], acc[i][j], 0, 0, 0);
        }

        // epilogue: out = acc*s + w(1-w)*dA[m]*dB[n]
        #pragma unroll
        for (int i = 0; i < 4; ++i) {
            #pragma unroll
            for (int reg = 0; reg < 4; ++reg) {
                const int m = qm * 64 + i * 16 + lq * 4 + reg;
                const float da = aw * dA[m];
                float* rowp = cov_out + cbase + (size_t)(a0 + m) * A + b0;
                #pragma unroll
                for (int j = 0; j < 4; ++j) {
                    const int n = qn * 64 + j * 16 + lr;
                    rowp[n] = acc[i][j][reg] * s + da * dB[n];
                }
            }
        }
    } else {
        // w == 0: new_cov = cov_in * (1-w)
        const float sc = omw;
        for (int t = tid; t < TM * TM / 4; t += 256) {
            const int r = t >> 5;            // 128 rows
            const int c4 = (t & 31) * 4;     // 32 float4s per row
            const size_t o = cbase + (size_t)(a0 + r) * A + b0 + c4;
            float4 co = *reinterpret_cast<const float4*>(&cov_in[o]);
            float4 res = make_float4(co.x * sc, co.y * sc, co.z * sc, co.w * sc);
            *reinterpret_cast<float4*>(&cov_out[o]) = res;
        }
    }
}

// ---------------- loss: 64 blocks, block-reduced, atomicAdd of mean directly into out[0] ----------------
__global__ __launch_bounds__(256) void loss_kernel(
    const float* __restrict__ y_s, const int* __restrict__ labels,
    float* __restrict__ out_loss0, int N, int C, float invN) {
    __shared__ float bsum[4];
    const int lane = threadIdx.x & 63;
    const int wv = threadIdx.x >> 6;
    const int gw = blockIdx.x * 4 + wv;
    const int nwaves = gridDim.x * 4;
    float wsum = 0.f;
    for (int r = gw; r < N; r += nwaves) {
        const float* row = y_s + (size_t)r * C;
        float m = -1e30f;
        for (int col = lane; col < C; col += 64) m = fmaxf(m, row[col]);
        #pragma unroll
        for (int off = 32; off > 0; off >>= 1) m = fmaxf(m, __shfl_xor(m, off));
        float se = 0.f;
        for (int col = lane; col < C; col += 64) se += __expf(row[col] - m);
        #pragma unroll
        for (int off = 32; off > 0; off >>= 1) se += __shfl_xor(se, off);
        if (lane == 0) wsum += -(row[labels[r]] - m - __logf(se));
    }
    if (lane == 0) bsum[wv] = wsum;
    __syncthreads();
    if (threadIdx.x == 0) {
        float t = (bsum[0] + bsum[1] + bsum[2] + bsum[3]) * invN;
        atomicAdd(out_loss0, t);
    }
}

extern "C" void kernel_launch(void* const* d_in, const int* in_sizes, int n_in,
                              void* d_out, int out_size, void* d_ws, size_t ws_size,
                              hipStream_t stream) {
    const float* feats  = (const float*)d_in[0];
    const float* y_s    = (const float*)d_in[1];
    const float* cov_in = (const float*)d_in[2];
    const float* Ave_in = (const float*)d_in[3];
    const float* Amount = (const float*)d_in[4];
    const int*   labels = (const int*)d_in[5];

    const int C = in_sizes[4];
    const int N = in_sizes[5];
    const int A = in_sizes[3] / C;

    float* out      = (float*)d_out;
    float* out_loss = out;
    float* out_cov  = out + 1;
    float* out_ave  = out_cov + (size_t)C * A * A;
    float* out_amt  = out_ave + (size_t)C * A;

    char* w8 = (char*)d_ws;
    int* offsets    = (int*)w8;   w8 += (size_t)(C + 1) * sizeof(int);
    int* idx_sorted = (int*)w8;   w8 += (size_t)N * sizeof(int);
    float* w_arr    = (float*)w8; w8 += (size_t)C * sizeof(float);
    float* inv_cs   = (float*)w8; w8 += (size_t)C * sizeof(float);
    float* ave_new  = (float*)w8; w8 += (size_t)C * A * sizeof(float);

    prep_kernel<<<1, 1024, 0, stream>>>(labels, Amount, offsets, idx_sorted,
                                        w_arr, inv_cs, out_amt, out_loss, N, C);
    ave_kernel<<<dim3(A / 128, C), 128, 0, stream>>>(feats, Ave_in, idx_sorted, offsets,
                                                     w_arr, inv_cs, ave_new, out_ave, A);
    dim3 grid(A / TM, A / TM, C);
    cov_kernel<<<grid, 256, 0, stream>>>(feats, cov_in, ave_new, Ave_in, idx_sorted, offsets,
                                         w_arr, inv_cs, out_cov, A);
    loss_kernel<<<64, 256, 0, stream>>>(y_s, labels, out_loss, N, C, 1.f / (float)N);
}